// Round 1
// baseline (199.908 us; speedup 1.0000x reference)
//
#include <hip/hip_runtime.h>

// FSUMatMul one-cycle. Exact identity: with in_f = scale_carry = 2048 and
// DEPTH=12 (bound 4095 > 2048), the emitted bit is
//   out[b,o] = (sum_k XNOR(x[b,k], path[o,k]) == in_f)
//            = (x row b bit-identical to path row o, all 2048 bits).
//
// Single fused kernel, ZERO workspace use (tests whether the 256 MiB d_ws
// poison fill drops out of the timed loop), one launch instead of two.
// Each block re-packs the word-0 (first 64 columns) of its o-tile / b-tile
// into LDS via ballot (distinct footprint 2 MB -> L2-resident; redundant
// re-reads ~128 MB of L2 traffic ~= 3.7 us aggregate), then compares and
// streams the mandatory 67 MB output with nontemporal float4 stores (output
// is write-once; NT keeps packed-source lines hot in L2).
//
// Fast path compares only the first 64 bits (match prob ~2^-64/pair); a
// slow path re-verifies bits 64..2047 from pristine x/w so the kernel is
// exact for ANY input, ~never executed for this one.

#define BATCH 4096
#define INF   2048
#define OUTF  4096

#define BTILE 32     // output rows per block
#define OTILE 1024   // output cols per block
// grid = (OUTF/OTILE, BATCH/BTILE) = (4, 128) = 512 blocks, 2 per CU

typedef float f4 __attribute__((ext_vector_type(4)));

__global__ __launch_bounds__(256) void fsu_fused(
    const float* __restrict__ x, const float* __restrict__ w,
    const float* __restrict__ rng, float* __restrict__ out)
{
    __shared__ unsigned long long pp[OTILE];  // packed word-0 of path rows
    __shared__ unsigned long long xq[BTILE];  // packed word-0 of x rows

    const int tid   = threadIdx.x;
    const int lane  = tid & 63;
    const int wav   = tid >> 6;               // 0..3
    const int obase = blockIdx.x * OTILE;
    const int bbase = blockIdx.y * BTILE;
    const float r   = rng[0];                 // uniform scalar, 128.0

    // ---- pack word-0 of this block's 1024 w-rows: one ballot per row ----
    // wave w owns local rows [w*256, w*256+256); 256B coalesced load per row.
    {
        const int lr0 = wav * (OTILE / 4);
        #pragma unroll 8
        for (int t = 0; t < OTILE / 4; ++t) {
            const int lr = lr0 + t;
            const float v = w[(size_t)(obase + lr) * INF + lane];
            // BinGen/BSGen: source = round((w+1)*0.5*2^WIDTH); path = source > rng.
            // rintf = round-half-even matches jnp.round; *0.5 and *256 exact.
            const float s = rintf((v + 1.0f) * 0.5f * 256.0f);
            const unsigned long long bb = __ballot(s > r);
            if (lane == 0) pp[lr] = bb;
        }
    }
    // ---- pack word-0 of this block's 32 x-rows ----
    {
        const int lb0 = wav * (BTILE / 4);
        #pragma unroll
        for (int t = 0; t < BTILE / 4; ++t) {
            const int lb = lb0 + t;
            const float v = x[(size_t)(bbase + lb) * INF + lane];
            const unsigned long long bb = __ballot(v != 0.0f);
            if (lane == 0) xq[lb] = bb;
        }
    }
    __syncthreads();

    // ---- compare + stream output: thread owns 4 consecutive o columns ----
    const int ol = tid * 4;
    const unsigned long long p0 = pp[ol + 0];
    const unsigned long long p1 = pp[ol + 1];
    const unsigned long long p2 = pp[ol + 2];
    const unsigned long long p3 = pp[ol + 3];
    const int o0 = obase + ol;

    for (int i = 0; i < BTILE; ++i) {
        const int b = bbase + i;
        const unsigned long long xv = xq[i];   // LDS broadcast, conflict-free
        bool eq0 = (p0 == xv);
        bool eq1 = (p1 == xv);
        bool eq2 = (p2 == xv);
        bool eq3 = (p3 == xv);
        if (eq0 | eq1 | eq2 | eq3) {           // ~never taken
            bool eq[4] = {eq0, eq1, eq2, eq3};
            for (int j = 0; j < 4; ++j) {
                if (!eq[j]) continue;
                const int o = o0 + j;
                bool all = true;
                for (int k = 64; k < INF; ++k) {
                    const bool xb = x[(size_t)b * INF + k] != 0.0f;
                    const bool pb =
                        rintf((w[(size_t)o * INF + k] + 1.0f) * 0.5f * 256.0f) > r;
                    all = all && (xb == pb);
                }
                eq[j] = all;
            }
            eq0 = eq[0]; eq1 = eq[1]; eq2 = eq[2]; eq3 = eq[3];
        }
        f4 res = { eq0 ? 1.0f : 0.0f, eq1 ? 1.0f : 0.0f,
                   eq2 ? 1.0f : 0.0f, eq3 ? 1.0f : 0.0f };
        // 16B/lane, 1KB/wave-instr contiguous; NT bypasses L2 (write-once).
        __builtin_nontemporal_store(
            res, reinterpret_cast<f4*>(out + (size_t)b * OUTF + o0));
    }
}

extern "C" void kernel_launch(void* const* d_in, const int* in_sizes, int n_in,
                              void* d_out, int out_size, void* d_ws, size_t ws_size,
                              hipStream_t stream) {
    const float* x   = (const float*)d_in[0];   // (4096, 2048) {0,1}
    const float* w   = (const float*)d_in[1];   // (4096, 2048) [-1,1]
    const float* rng = (const float*)d_in[2];   // scalar 128.0
    float* out = (float*)d_out;                 // (4096, 4096)

    (void)d_ws; (void)ws_size;                  // deliberately unused

    fsu_fused<<<dim3(OUTF / OTILE, BATCH / BTILE), dim3(256), 0, stream>>>(
        x, w, rng, out);
}

// Round 2
// 109.597 us; speedup vs baseline: 1.8240x; 1.8240x over previous
//
#include <hip/hip_runtime.h>

// FSUMatMul one-cycle. Exact identity: with in_f = scale_carry = 2048 and
// DEPTH=12 (bound 4095 > 2048), the emitted bit is
//   out[b,o] = (sum_k XNOR(x[b,k], path[o,k]) == in_f)
//            = (x row b bit-identical to path row o, all 2048 bits).
//
// Two-kernel structure (round-0 shape, re-tuned). Round-1 fusion was
// latency-bound (512 blocks, serial 256-iter pack chain per wave, 125 us).
// Harness evidence: the 256 MiB d_ws poison fill runs whether or not we
// touch d_ws (fixed ~75 us in-graph reset) -> using d_ws costs nothing.
//
// pack0: one wave packs the first 64 columns of one row via ballot (2 MB
//        reads total, 8192 waves -> a few us).
// cmp:   2048 blocks (full occupancy), 8 rows x 4 cols per thread,
//        nontemporal float4 stores for the mandatory 67 MB write.
// Fast path compares word 0 only (match prob ~2^-64/pair); rare path
// re-verifies bits 64..2047 from pristine x/w -> exact for ANY input.

#define BATCH 4096
#define INF   2048
#define OUTF  4096

typedef unsigned long long u64;
typedef float f4 __attribute__((ext_vector_type(4)));

// ids [0, BATCH) -> x rows, [BATCH, BATCH+OUTF) -> w rows.
__global__ __launch_bounds__(256) void pack0_kernel(
    const float* __restrict__ x, const float* __restrict__ w,
    const float* __restrict__ rng,
    u64* __restrict__ xp0, u64* __restrict__ pp0)
{
    const int lane = threadIdx.x & 63;
    const int wav  = threadIdx.x >> 6;
    const int id   = blockIdx.x * 4 + wav;          // wave-uniform

    if (id < BATCH) {
        const float v = x[(size_t)id * INF + lane]; // 256B coalesced per wave
        const u64 b = __ballot(v != 0.0f);
        if (lane == 0) xp0[id] = b;
    } else {
        const int o = id - BATCH;
        const float v = w[(size_t)o * INF + lane];
        // BinGen/BSGen: source = round((w+1)*0.5*2^WIDTH); path = source > rng.
        // rintf = round-half-even matches jnp.round; *0.5 and *256 exact.
        const float s = rintf((v + 1.0f) * 0.5f * 256.0f);
        const u64 b = __ballot(s > rng[0]);
        if (lane == 0) pp0[o] = b;
    }
}

// Thread owns 4 consecutive o-cols x 8 b-rows. Grid (4, 512) = 2048 blocks
// = 8 blocks/CU wave-slots -> full 32-wave occupancy for the store stream.
__global__ __launch_bounds__(256) void cmp_kernel(
    const u64* __restrict__ xp0, const u64* __restrict__ pp0,
    const float* __restrict__ x, const float* __restrict__ w,
    const float* __restrict__ rng, float* __restrict__ out)
{
    const int tid = threadIdx.x;
    const int o0  = blockIdx.x * 1024 + tid * 4;
    const int b0  = blockIdx.y * 8;

    // word-0 of 4 consecutive path rows: 32B/thread contiguous, L2-hot
    const u64 p0 = pp0[o0 + 0];
    const u64 p1 = pp0[o0 + 1];
    const u64 p2 = pp0[o0 + 2];
    const u64 p3 = pp0[o0 + 3];

    #pragma unroll
    for (int i = 0; i < 8; ++i) {
        const int b = b0 + i;
        const u64 xv = xp0[b];                  // block-uniform -> s_load
        bool eq0 = (p0 == xv);
        bool eq1 = (p1 == xv);
        bool eq2 = (p2 == xv);
        bool eq3 = (p3 == xv);
        if (eq0 | eq1 | eq2 | eq3) {            // ~never taken
            const float r = rng[0];
            bool eq[4] = {eq0, eq1, eq2, eq3};
            for (int j = 0; j < 4; ++j) {
                if (!eq[j]) continue;
                const int o = o0 + j;
                bool all = true;
                for (int k = 64; k < INF; ++k) {
                    const bool xb = x[(size_t)b * INF + k] != 0.0f;
                    const bool pb =
                        rintf((w[(size_t)o * INF + k] + 1.0f) * 0.5f * 256.0f) > r;
                    all = all && (xb == pb);
                }
                eq[j] = all;
            }
            eq0 = eq[0]; eq1 = eq[1]; eq2 = eq[2]; eq3 = eq[3];
        }
        f4 res = { eq0 ? 1.0f : 0.0f, eq1 ? 1.0f : 0.0f,
                   eq2 ? 1.0f : 0.0f, eq3 ? 1.0f : 0.0f };
        // 16B/lane, 1KB/wave-instr contiguous; NT: write-once stream.
        __builtin_nontemporal_store(
            res, reinterpret_cast<f4*>(out + (size_t)b * OUTF + o0));
    }
}

extern "C" void kernel_launch(void* const* d_in, const int* in_sizes, int n_in,
                              void* d_out, int out_size, void* d_ws, size_t ws_size,
                              hipStream_t stream) {
    const float* x   = (const float*)d_in[0];   // (4096, 2048) {0,1}
    const float* w   = (const float*)d_in[1];   // (4096, 2048) [-1,1]
    const float* rng = (const float*)d_in[2];   // scalar 128.0
    float* out = (float*)d_out;                 // (4096, 4096)

    u64* xp0 = (u64*)d_ws;                      // 4096 u64 = 32KB
    u64* pp0 = xp0 + BATCH;                     // 4096 u64 = 32KB

    // 8192 word-0 packs, 4 waves per 256-thread block -> 2048 blocks
    pack0_kernel<<<dim3((BATCH + OUTF) / 4), dim3(256), 0, stream>>>(
        x, w, rng, xp0, pp0);

    // grid: 4 o-tiles (1024 cols) x 512 b-tiles (8 rows each)
    cmp_kernel<<<dim3(OUTF / 1024, BATCH / 8), dim3(256), 0, stream>>>(
        xp0, pp0, x, w, rng, out);
}

// Round 3
// 107.188 us; speedup vs baseline: 1.8650x; 1.0225x over previous
//
#include <hip/hip_runtime.h>

// FSUMatMul one-cycle. Exact identity: with in_f = scale_carry = 2048 and
// DEPTH=12 (bound 4095 > 2048), the emitted bit is
//   out[b,o] = (sum_k XNOR(x[b,k], path[o,k]) == in_f)
//            = (x row b bit-identical to path row o, all 2048 bits).
//
// Two-kernel structure. Fixed harness reset (~75 us: 256 MiB ws poison +
// out poison + input restore) dominates end-to-end; controllable slice is
// pack (~3 us) + the mandatory 67 MB out write + launch gaps.
//
// Round-3 A/B: round 2 used nontemporal stores (bypass L2 -> every line
// forced to HBM during the kernel). Out was just poison-filled, so its
// lines are dirty in L2/L3; regular write-back stores retire at cache rate
// and drain lazily. Single change vs round 2: NT -> regular float4 stores.
//
// Fast path compares word 0 only (match prob ~2^-64/pair); rare path
// re-verifies bits 64..2047 from pristine x/w -> exact for ANY input.

#define BATCH 4096
#define INF   2048
#define OUTF  4096

typedef unsigned long long u64;
typedef float f4 __attribute__((ext_vector_type(4)));

// ids [0, BATCH) -> x rows, [BATCH, BATCH+OUTF) -> w rows.
__global__ __launch_bounds__(256) void pack0_kernel(
    const float* __restrict__ x, const float* __restrict__ w,
    const float* __restrict__ rng,
    u64* __restrict__ xp0, u64* __restrict__ pp0)
{
    const int lane = threadIdx.x & 63;
    const int wav  = threadIdx.x >> 6;
    const int id   = blockIdx.x * 4 + wav;          // wave-uniform

    if (id < BATCH) {
        const float v = x[(size_t)id * INF + lane]; // 256B coalesced per wave
        const u64 b = __ballot(v != 0.0f);
        if (lane == 0) xp0[id] = b;
    } else {
        const int o = id - BATCH;
        const float v = w[(size_t)o * INF + lane];
        // BinGen/BSGen: source = round((w+1)*0.5*2^WIDTH); path = source > rng.
        // rintf = round-half-even matches jnp.round; *0.5 and *256 exact.
        const float s = rintf((v + 1.0f) * 0.5f * 256.0f);
        const u64 b = __ballot(s > rng[0]);
        if (lane == 0) pp0[o] = b;
    }
}

// Thread owns 4 consecutive o-cols x 8 b-rows. Grid (4, 512) = 2048 blocks
// -> full occupancy for the store stream.
__global__ __launch_bounds__(256) void cmp_kernel(
    const u64* __restrict__ xp0, const u64* __restrict__ pp0,
    const float* __restrict__ x, const float* __restrict__ w,
    const float* __restrict__ rng, float* __restrict__ out)
{
    const int tid = threadIdx.x;
    const int o0  = blockIdx.x * 1024 + tid * 4;
    const int b0  = blockIdx.y * 8;

    // word-0 of 4 consecutive path rows: 32B/thread contiguous, L2-hot
    const u64 p0 = pp0[o0 + 0];
    const u64 p1 = pp0[o0 + 1];
    const u64 p2 = pp0[o0 + 2];
    const u64 p3 = pp0[o0 + 3];

    #pragma unroll
    for (int i = 0; i < 8; ++i) {
        const int b = b0 + i;
        const u64 xv = xp0[b];                  // block-uniform -> s_load
        bool eq0 = (p0 == xv);
        bool eq1 = (p1 == xv);
        bool eq2 = (p2 == xv);
        bool eq3 = (p3 == xv);
        if (eq0 | eq1 | eq2 | eq3) {            // ~never taken
            const float r = rng[0];
            bool eq[4] = {eq0, eq1, eq2, eq3};
            for (int j = 0; j < 4; ++j) {
                if (!eq[j]) continue;
                const int o = o0 + j;
                bool all = true;
                for (int k = 64; k < INF; ++k) {
                    const bool xb = x[(size_t)b * INF + k] != 0.0f;
                    const bool pb =
                        rintf((w[(size_t)o * INF + k] + 1.0f) * 0.5f * 256.0f) > r;
                    all = all && (xb == pb);
                }
                eq[j] = all;
            }
            eq0 = eq[0]; eq1 = eq[1]; eq2 = eq[2]; eq3 = eq[3];
        }
        f4 res = { eq0 ? 1.0f : 0.0f, eq1 ? 1.0f : 0.0f,
                   eq2 ? 1.0f : 0.0f, eq3 ? 1.0f : 0.0f };
        // Regular write-back store: retire into L2/L3 (out lines are
        // cache-resident from the poison fill), drain lazily.
        *reinterpret_cast<f4*>(out + (size_t)b * OUTF + o0) = res;
    }
}

extern "C" void kernel_launch(void* const* d_in, const int* in_sizes, int n_in,
                              void* d_out, int out_size, void* d_ws, size_t ws_size,
                              hipStream_t stream) {
    const float* x   = (const float*)d_in[0];   // (4096, 2048) {0,1}
    const float* w   = (const float*)d_in[1];   // (4096, 2048) [-1,1]
    const float* rng = (const float*)d_in[2];   // scalar 128.0
    float* out = (float*)d_out;                 // (4096, 4096)

    u64* xp0 = (u64*)d_ws;                      // 4096 u64 = 32KB
    u64* pp0 = xp0 + BATCH;                     // 4096 u64 = 32KB

    // 8192 word-0 packs, 4 waves per 256-thread block -> 2048 blocks
    pack0_kernel<<<dim3((BATCH + OUTF) / 4), dim3(256), 0, stream>>>(
        x, w, rng, xp0, pp0);

    // grid: 4 o-tiles (1024 cols) x 512 b-tiles (8 rows each)
    cmp_kernel<<<dim3(OUTF / 1024, BATCH / 8), dim3(256), 0, stream>>>(
        xp0, pp0, x, w, rng, out);
}

// Round 4
// 106.820 us; speedup vs baseline: 1.8714x; 1.0034x over previous
//
#include <hip/hip_runtime.h>

// FSUMatMul one-cycle. Exact identity: with in_f = scale_carry = 2048 and
// DEPTH=12 (bound 4095 > 2048), the emitted bit is
//   out[b,o] = (sum_k XNOR(x[b,k], path[o,k]) == in_f)
//            = (x row b bit-identical to path row o, all 2048 bits).
//
// Round 4: the output is all-zeros except at full-row matches (prob ~0).
// Delegate the mandatory 67 MB write to hipMemsetAsync (rocclr fill hits
// 6.5 TB/s at 8% occupancy per rocprof -> ~10.5 us), and reduce our compute
// to: pack word-0 of all rows (2 MB reads) + 16.7M u64 compares (~2-3 us).
// A word-0 hit (~2^-64/pair) is re-verified against bits 64..2047 from the
// pristine x/w and the lone 1.0f is scatter-written -> exact for ANY input.

#define BATCH 4096
#define INF   2048
#define OUTF  4096

typedef unsigned long long u64;

// ids [0, BATCH) -> x rows, [BATCH, BATCH+OUTF) -> w rows.
__global__ __launch_bounds__(256) void pack0_kernel(
    const float* __restrict__ x, const float* __restrict__ w,
    const float* __restrict__ rng,
    u64* __restrict__ xp0, u64* __restrict__ pp0)
{
    const int lane = threadIdx.x & 63;
    const int wav  = threadIdx.x >> 6;
    const int id   = blockIdx.x * 4 + wav;          // wave-uniform

    if (id < BATCH) {
        const float v = x[(size_t)id * INF + lane]; // 256B coalesced per wave
        const u64 b = __ballot(v != 0.0f);
        if (lane == 0) xp0[id] = b;
    } else {
        const int o = id - BATCH;
        const float v = w[(size_t)o * INF + lane];
        // BinGen/BSGen: source = round((w+1)*0.5*2^WIDTH); path = source > rng.
        // rintf = round-half-even matches jnp.round; *0.5 and *256 exact.
        const float s = rintf((v + 1.0f) * 0.5f * 256.0f);
        const u64 b = __ballot(s > rng[0]);
        if (lane == 0) pp0[o] = b;
    }
}

// Grid (OUTF/256, BATCH/64) = (16, 64) = 1024 blocks. Thread owns one o
// column (its word-0 in a register) and scans 64 b rows from LDS.
// Total compares = 4096 x 4096 = 16.7M; all operands L2-hot.
__global__ __launch_bounds__(256) void match_kernel(
    const u64* __restrict__ xp0, const u64* __restrict__ pp0,
    const float* __restrict__ x, const float* __restrict__ w,
    const float* __restrict__ rng, float* __restrict__ out)
{
    __shared__ u64 xq[64];

    const int tid = threadIdx.x;
    const int o   = blockIdx.x * 256 + tid;
    const int b0  = blockIdx.y * 64;

    if (tid < 64) xq[tid] = xp0[b0 + tid];    // one coalesced 512B load
    const u64 p = pp0[o];                     // 2KB/block coalesced, L2-hot
    __syncthreads();

    #pragma unroll 8
    for (int i = 0; i < 64; ++i) {
        if (p == xq[i]) {                     // LDS broadcast; ~never true
            const int b = b0 + i;
            const float r = rng[0];
            bool all = true;
            for (int k = 64; k < INF; ++k) {
                const bool xb = x[(size_t)b * INF + k] != 0.0f;
                const bool pb =
                    rintf((w[(size_t)o * INF + k] + 1.0f) * 0.5f * 256.0f) > r;
                all = all && (xb == pb);
            }
            if (all) out[(size_t)b * OUTF + o] = 1.0f;  // lone scatter store
        }
    }
}

extern "C" void kernel_launch(void* const* d_in, const int* in_sizes, int n_in,
                              void* d_out, int out_size, void* d_ws, size_t ws_size,
                              hipStream_t stream) {
    const float* x   = (const float*)d_in[0];   // (4096, 2048) {0,1}
    const float* w   = (const float*)d_in[1];   // (4096, 2048) [-1,1]
    const float* rng = (const float*)d_in[2];   // scalar 128.0
    float* out = (float*)d_out;                 // (4096, 4096)

    u64* xp0 = (u64*)d_ws;                      // 4096 u64 = 32KB
    u64* pp0 = xp0 + BATCH;                     // 4096 u64 = 32KB

    // Mandatory 67 MB output write via the 6.5 TB/s rocclr fill (0.0f == 0x0).
    hipMemsetAsync(out, 0, (size_t)out_size, stream);

    // 8192 word-0 packs, 4 waves per 256-thread block -> 2048 blocks
    pack0_kernel<<<dim3((BATCH + OUTF) / 4), dim3(256), 0, stream>>>(
        x, w, rng, xp0, pp0);

    // 16.7M word-0 compares; writes nothing unless a full-row match exists
    match_kernel<<<dim3(OUTF / 256, BATCH / 64), dim3(256), 0, stream>>>(
        xp0, pp0, x, w, rng, out);
}